// Round 9
// baseline (464.547 us; speedup 1.0000x reference)
//
#include <hip/hip_runtime.h>
#include <math.h>

// CapsLayer dynamic routing, MI355X fp32.
// x: [64, 2048, 8]  W: [2048, 32, 8, 16]  out: [64, 32, 16]
// Never materialize u_hat (256 MB); recompute per routing pass.
// R11: 1-wave blocks, zero in-loop barriers, in-wave softmax.
// Evidence: R5 (reg-direct) 47.6us, R9 (LDS dbuf + counted vmcnt) 54.6us,
// R10 (LDS single) 50.9us — three W-feed structures, same wall; MODE0 ==
// MODE1 every time (softmax/barriers not the cost); Occ stuck ~33%. The
// invariant was the 256-thread 4-wave lockstep block. This round: lane =
// rp(1b)|n(5b) puts all 32 capsules in ONE wave -> softmax = 5 shfl_xor,
// no wsum LDS, no barriers; 64-thread blocks, 4096 of them (16/CU, all
// resident, one round), every wave independent.
//   BC=4 rows/block (lane owns 2 rows x full 16e), ICH=8 -> NIC=256,
//   P = 32 MB (proven R3-R8 workspace footprint).
//   v staged in LDS (8 KB) to keep VGPR ~110 < 128 cap of (64,4).
//   W read from global per-d (4 float4, unroll 2); wave's 16 KB tile is
//   L1-resident across its 32 touching instructions.
// Tripwires: FETCH < 100 MB (else spill); VGPR <= 128; absmax <= 1e-3.
// Kept: unroll-1 guard on ii, aws elimination via dot linearity (pass 3 =
// MODE1 with vin = v0+v1), parallel 512-block reduce_squash.

#define B_TOT 64
#define I_TOT 2048
#define D_IN  8
#define NC    32
#define EV    16
#define OD    (NC*EV)      // 512 outputs per b
#define BC    4            // batch rows per block (2 per lane via rp)
#define NBC   (B_TOT/BC)   // 16 b-chunks
#define ICH   8            // i's per block
#define NIC   (I_TOT/ICH)  // 256 i-chunks

__device__ __forceinline__ void fma4(float4& acc, float a, const float4& w) {
    acc.x = fmaf(a, w.x, acc.x);
    acc.y = fmaf(a, w.y, acc.y);
    acc.z = fmaf(a, w.z, acc.z);
    acc.w = fmaf(a, w.w, acc.w);
}

// MODE 0: c uniform (iter 0)              -> P partials
// MODE 1: c = softmax_n(u . vin)          -> P partials
//         (iter 2 uses vin = v0+v1: dot is linear, so no logit carry needed)
template <int MODE>
__global__ __launch_bounds__(64, 4)   // cap 128 VGPR; natural ~110 fits
void route_pass(const float* __restrict__ x, const float* __restrict__ W,
                float* __restrict__ P, const float* __restrict__ vin)
{
    __shared__ __align__(16) float xl[BC * ICH * D_IN];   // 1 KB
    __shared__ __align__(16) float vl[BC * OD];           // 8 KB (MODE1)

    const int t  = threadIdx.x;          // 0..63 (one wave)
    // XCD swizzle: blk%8 == ic%8 (NIC=256), bc-siblings of an ic share L2.
    const int ic = blockIdx.x & (NIC - 1);   // 0..255
    const int bc = blockIdx.x >> 8;          // 0..15
    const int b0 = bc * BC;
    const int i0 = ic * ICH;
    const int n  = t & 31;               // capsule, fully in-wave
    const int rp = t >> 5;               // row-pair: this lane owns rows rp*2, rp*2+1

    // ---- stage x[b0..b0+3][i0..i0+7][0..7] = 64 float4, one per lane ----
    {
        const int row = t >> 4;          // 0..3
        const int rem = t & 15;
        const int i = rem >> 1, dh = rem & 1;
        *(float4*)&xl[(row * ICH + i) * D_IN + dh * 4] =
            *(const float4*)&x[((size_t)(b0 + row) * I_TOT + i0 + i) * D_IN + dh * 4];
    }
    // ---- stage v[b0..b0+3][*] = 512 float4, 8 per lane (coalesced) ----
    if (MODE == 1) {
        #pragma unroll
        for (int j = 0; j < 8; ++j) {
            const int f4 = j * 64 + t;   // [row][128] float4 layout
            ((float4*)vl)[f4] = ((const float4*)vin)[(size_t)b0 * (OD / 4) + f4];
        }
    }
    __syncthreads();   // the ONLY barrier in the kernel

    float4 sacc[2][4];
    #pragma unroll
    for (int r = 0; r < 2; ++r)
        #pragma unroll
        for (int q = 0; q < 4; ++q) sacc[r][q] = make_float4(0.f, 0.f, 0.f, 0.f);

    const float* Wn = W + (size_t)i0 * 4096 + n * 128;   // W[i0][n][0][0]

    // unroll 1 is load-bearing: full unroll hoists 32 float4 W loads -> spill
    // (R3/R4 disaster). Latency hidden by 16 independent waves/CU.
    #pragma unroll 1
    for (int ii = 0; ii < ICH; ++ii) {
        const float* Wi = Wn + (size_t)ii * 4096;
        float4 u[2][4];
        #pragma unroll
        for (int r = 0; r < 2; ++r)
            #pragma unroll
            for (int q = 0; q < 4; ++q) u[r][q] = make_float4(0.f, 0.f, 0.f, 0.f);

        // per d: 4 float4 of W (this capsule's full 16e row) + 2 x scalars.
        // unroll 2: 8 float4 W live (32 regs) -> two d's of loads in flight.
        #pragma unroll 2
        for (int d = 0; d < 8; ++d) {
            const float4 w0 = *(const float4*)&Wi[d * 16];
            const float4 w1 = *(const float4*)&Wi[d * 16 + 4];
            const float4 w2 = *(const float4*)&Wi[d * 16 + 8];
            const float4 w3 = *(const float4*)&Wi[d * 16 + 12];
            const float x0 = xl[((rp * 2 + 0) * ICH + ii) * D_IN + d];
            const float x1 = xl[((rp * 2 + 1) * ICH + ii) * D_IN + d];
            fma4(u[0][0], x0, w0); fma4(u[0][1], x0, w1);
            fma4(u[0][2], x0, w2); fma4(u[0][3], x0, w3);
            fma4(u[1][0], x1, w0); fma4(u[1][1], x1, w1);
            fma4(u[1][2], x1, w2); fma4(u[1][3], x1, w3);
        }

        if (MODE == 0) {
            #pragma unroll
            for (int r = 0; r < 2; ++r)
                #pragma unroll
                for (int q = 0; q < 4; ++q) {
                    sacc[r][q].x += u[r][q].x; sacc[r][q].y += u[r][q].y;
                    sacc[r][q].z += u[r][q].z; sacc[r][q].w += u[r][q].w;
                }
        } else {
            #pragma unroll
            for (int r = 0; r < 2; ++r) {
                const float4* vrow = (const float4*)&vl[(rp * 2 + r) * OD + n * EV];
                const float4 v0 = vrow[0], v1 = vrow[1], v2 = vrow[2], v3 = vrow[3];
                // a = dot(u, v) over all 16 e — fully in-lane, no shuffle
                float a = u[r][0].x*v0.x + u[r][0].y*v0.y + u[r][0].z*v0.z + u[r][0].w*v0.w
                        + u[r][1].x*v1.x + u[r][1].y*v1.y + u[r][1].z*v1.z + u[r][1].w*v1.w
                        + u[r][2].x*v2.x + u[r][2].y*v2.y + u[r][2].z*v2.z + u[r][2].w*v2.w
                        + u[r][3].x*v3.x + u[r][3].y*v3.y + u[r][3].z*v3.z + u[r][3].w*v3.w;
                // softmax over n: all 32 capsules are lanes 0..31 of this half
                const float e = __expf(a);
                float s = e;
                s += __shfl_xor(s, 1, 64);
                s += __shfl_xor(s, 2, 64);
                s += __shfl_xor(s, 4, 64);
                s += __shfl_xor(s, 8, 64);
                s += __shfl_xor(s, 16, 64);
                const float c = __fdividef(e, s);
                fma4(sacc[r][0], c, u[r][0]); fma4(sacc[r][1], c, u[r][1]);
                fma4(sacc[r][2], c, u[r][2]); fma4(sacc[r][3], c, u[r][3]);
            }
        }
    }

    // ---- write partials: P[ic][b][o] ----
    #pragma unroll
    for (int r = 0; r < 2; ++r)
        #pragma unroll
        for (int q = 0; q < 4; ++q)
            *(float4*)&P[((size_t)ic * B_TOT + b0 + rp * 2 + r) * OD + n * EV + q * 4]
                = sacc[r][q];
}

// Reduce partials over 256 i-chunks, then squash per (b, n).
// Grid: 64 b x 8 output-slices = 512 blocks (2/CU, all CUs busy).
// If addsrc != null, out = squash(...) + addsrc  (used to produce v0+v1).
__global__ __launch_bounds__(256, 4)
void reduce_squash(const float* __restrict__ P, float* __restrict__ dst,
                   const float* __restrict__ addsrc, float pre)
{
    __shared__ float red[256];
    const int b   = blockIdx.x >> 3;
    const int oq  = blockIdx.x & 7;
    const int t   = threadIdx.x;
    const int o   = oq * 64 + (t & 63);
    const int icq = t >> 6;                       // 0..3
    const size_t stride = (size_t)B_TOT * OD;     // per-ic stride in floats

    float s = 0.f;
    size_t base = ((size_t)(icq * 64) * B_TOT + b) * OD + o;
    #pragma unroll 8
    for (int k = 0; k < 64; ++k) s += P[base + (size_t)k * stride];
    red[t] = s;
    __syncthreads();

    if (t < 64) {
        float v = red[t] + red[t + 64] + red[t + 128] + red[t + 192];
        v *= pre;
        // squared norm over e (16 consecutive lanes = one capsule)
        float q2 = v * v;
        q2 += __shfl_xor(q2, 1, 64);
        q2 += __shfl_xor(q2, 2, 64);
        q2 += __shfl_xor(q2, 4, 64);
        q2 += __shfl_xor(q2, 8, 64);
        float sc = q2 / ((1.0f + q2) * sqrtf(q2));
        float outv = v * sc;
        if (addsrc) outv += addsrc[b * OD + o];
        dst[b * OD + o] = outv;
    }
}

extern "C" void kernel_launch(void* const* d_in, const int* in_sizes, int n_in,
                              void* d_out, int out_size, void* d_ws, size_t ws_size,
                              hipStream_t stream) {
    const float* x = (const float*)d_in[0];
    const float* W = (const float*)d_in[1];
    float* out = (float*)d_out;

    char* ws = (char*)d_ws;
    float* P  = (float*)ws;                               // NIC*64*512*4 = 32 MB
    float* v0 = (float*)(ws + (size_t)32 * 1024 * 1024);  // 64*512*4 = 128 KB
    float* vs = v0 + B_TOT * OD;                          // v0 + v1

    dim3 rg(NBC * NIC), rb(64);    // 4096 1-wave blocks = 16 WGs/CU, one round
    dim3 sg(B_TOT * 8), sb(256);   // 512 blocks

    // iter 0: uniform c = 1/32
    route_pass<0><<<rg, rb, 0, stream>>>(x, W, P, nullptr);
    reduce_squash<<<sg, sb, 0, stream>>>(P, v0, nullptr, 1.0f / 32.0f);
    // iter 1: c = softmax(u.v0)
    route_pass<1><<<rg, rb, 0, stream>>>(x, W, P, v0);
    // vs = v0 + v1  (iter-2 logits: u.v0 + u.v1 = u.(v0+v1))
    reduce_squash<<<sg, sb, 0, stream>>>(P, vs, v0, 1.0f);
    // iter 2: c = softmax(u.(v0+v1)); final
    route_pass<1><<<rg, rb, 0, stream>>>(x, W, P, vs);
    reduce_squash<<<sg, sb, 0, stream>>>(P, out, nullptr, 1.0f);
}